// Round 1
// baseline (2311.750 us; speedup 1.0000x reference)
//
#include <hip/hip_runtime.h>
#include <math.h>

#define NVIEW 4
#define BATCH 4
#define NSEQ  256
#define CDIM  768
#define HEADS 12
#define HD    64

// ---------------------------------------------------------------------------
// LayerNorm: one block (256 thr) per row of 768
// ---------------------------------------------------------------------------
__device__ __forceinline__ void block_ln_row(const float* __restrict__ xrow,
                                             const float* __restrict__ g,
                                             const float* __restrict__ b,
                                             float* __restrict__ orow)
{
    const int t = threadIdx.x;
    float x0 = xrow[t], x1 = xrow[t + 256], x2 = xrow[t + 512];
    float s  = x0 + x1 + x2;
    float s2 = x0 * x0 + x1 * x1 + x2 * x2;
    #pragma unroll
    for (int off = 32; off > 0; off >>= 1) {
        s  += __shfl_down(s, off);
        s2 += __shfl_down(s2, off);
    }
    __shared__ float w1[4], w2[4];
    if ((t & 63) == 0) { w1[t >> 6] = s; w2[t >> 6] = s2; }
    __syncthreads();
    float S  = w1[0] + w1[1] + w1[2] + w1[3];
    float S2 = w2[0] + w2[1] + w2[2] + w2[3];
    float mean = S * (1.0f / 768.0f);
    float var  = S2 * (1.0f / 768.0f) - mean * mean;
    float inv  = rsqrtf(var + 1e-6f);
    orow[t]       = (x0 - mean) * inv * g[t]       + b[t];
    orow[t + 256] = (x1 - mean) * inv * g[t + 256] + b[t + 256];
    orow[t + 512] = (x2 - mean) * inv * g[t + 512] + b[t + 512];
}

// input X:[B,V,N,C] row (bb*4+v)*256+n  ->  output Xn:[V,B,N,C]
__global__ void ln1_kernel(const float* __restrict__ X, const float* __restrict__ g,
                           const float* __restrict__ b, float* __restrict__ Xn)
{
    int rid = blockIdx.x;
    int n  = rid & 255;
    int bv = rid >> 8;
    int bb = bv >> 2, v = bv & 3;
    const float* xrow = X + (long)rid * CDIM;
    float* orow = Xn + ((long)(v * 4 + bb) * 256 + n) * CDIM;
    block_ln_row(xrow, g, b, orow);
}

// input/output [V,B,N,C], per-view gamma/beta
__global__ void ln2_kernel(const float* __restrict__ Xin, const float* __restrict__ g,
                           const float* __restrict__ b, float* __restrict__ Out)
{
    int rid = blockIdx.x;
    int v = rid >> 10;  // B*N = 1024 rows per view
    const float* xrow = Xin + (long)rid * CDIM;
    block_ln_row(xrow, g + v * CDIM, b + v * CDIM, Out + (long)rid * CDIM);
}

// ---------------------------------------------------------------------------
// Grouped GEMM: out[v] = A[v] (M,K) * W[v]^T (N,K)  + epilogue
// EPI: 0=none 1=+bias 2=+bias,gelu 3=+bias,+resid 4=(+bias)*2
// block 256 threads, 64x64 tile, BK=16, 4x4 microtile
// ---------------------------------------------------------------------------
__device__ __forceinline__ float gelu_exact(float x)
{
    return 0.5f * x * (1.0f + erff(x * 0.70710678118654752f));
}

template <int EPI>
__launch_bounds__(256, 2)
__global__ void gemm_awt(const float* __restrict__ A, const float* __restrict__ W,
                         const float* __restrict__ bias, const float* __restrict__ resid,
                         float* __restrict__ out, int M, int N, int K,
                         long wStride, long wOff, int bStride, int bOff)
{
    const int v = blockIdx.z;
    const float* Av = A + (long)v * M * K;
    const float* Wv = W + (long)v * wStride + wOff;
    float* outv = out + (long)v * M * N;

    __shared__ float As[16][68];
    __shared__ float Bs[16][68];

    const int tid = threadIdx.x;
    const int tx = tid & 15;
    const int ty = tid >> 4;
    const int lr = tid >> 2;          // 0..63
    const int lc = (tid & 3) << 2;    // 0,4,8,12
    const int row0 = blockIdx.y * 64;
    const int col0 = blockIdx.x * 64;

    float acc[4][4] = {{0.f}};
    const float* aPtr = Av + (long)(row0 + lr) * K + lc;
    const float* wPtr = Wv + (long)(col0 + lr) * K + lc;

    for (int k0 = 0; k0 < K; k0 += 16) {
        float4 a4 = *(const float4*)(aPtr + k0);
        float4 w4 = *(const float4*)(wPtr + k0);
        As[lc + 0][lr] = a4.x; As[lc + 1][lr] = a4.y; As[lc + 2][lr] = a4.z; As[lc + 3][lr] = a4.w;
        Bs[lc + 0][lr] = w4.x; Bs[lc + 1][lr] = w4.y; Bs[lc + 2][lr] = w4.z; Bs[lc + 3][lr] = w4.w;
        __syncthreads();
        #pragma unroll
        for (int kk = 0; kk < 16; ++kk) {
            float4 a = *(const float4*)&As[kk][ty << 2];
            float4 w = *(const float4*)&Bs[kk][tx << 2];
            acc[0][0] += a.x * w.x; acc[0][1] += a.x * w.y; acc[0][2] += a.x * w.z; acc[0][3] += a.x * w.w;
            acc[1][0] += a.y * w.x; acc[1][1] += a.y * w.y; acc[1][2] += a.y * w.z; acc[1][3] += a.y * w.w;
            acc[2][0] += a.z * w.x; acc[2][1] += a.z * w.y; acc[2][2] += a.z * w.z; acc[2][3] += a.z * w.w;
            acc[3][0] += a.w * w.x; acc[3][1] += a.w * w.y; acc[3][2] += a.w * w.z; acc[3][3] += a.w * w.w;
        }
        __syncthreads();
    }

    #pragma unroll
    for (int i = 0; i < 4; ++i) {
        int row = row0 + (ty << 2) + i;
        int col = col0 + (tx << 2);
        float4 r4 = make_float4(acc[i][0], acc[i][1], acc[i][2], acc[i][3]);
        if (EPI >= 1) {
            const float* bv = bias + (long)v * bStride + bOff + col;
            r4.x += bv[0]; r4.y += bv[1]; r4.z += bv[2]; r4.w += bv[3];
        }
        if (EPI == 2) {
            r4.x = gelu_exact(r4.x); r4.y = gelu_exact(r4.y);
            r4.z = gelu_exact(r4.z); r4.w = gelu_exact(r4.w);
        } else if (EPI == 3) {
            float4 rr = *(const float4*)(resid + (long)v * M * N + (long)row * N + col);
            r4.x += rr.x; r4.y += rr.y; r4.z += rr.z; r4.w += rr.w;
        } else if (EPI == 4) {
            r4.x *= 2.0f; r4.y *= 2.0f; r4.z *= 2.0f; r4.w *= 2.0f;
        }
        *(float4*)(outv + (long)row * N + col) = r4;
    }
}

// ---------------------------------------------------------------------------
// Fusion attention: for query view i, ctx_mean = 1/4 * sum_j softmax(q_i k_j^T *s) v_j
// grid (nt=8, B*H=48, V=4); block 256; 32 query rows per block
// QKV layout [V,B,N,3C] with d = t*768 + h*64 + e
// ---------------------------------------------------------------------------
__launch_bounds__(256, 1)
__global__ void fusion_attn(const float* __restrict__ QKV, float* __restrict__ ctx)
{
    const int i  = blockIdx.z;
    const int b  = blockIdx.y / HEADS;
    const int h  = blockIdx.y % HEADS;
    const int nt = blockIdx.x;
    const int t  = threadIdx.x;

    __shared__ float qs[32][68];
    __shared__ float sc[32][257];
    __shared__ float kv[64][68];
    __shared__ float red[32][8];
    __shared__ float invsum[32];

    const int r  = t >> 3;   // 0..31  query row within tile
    const int g8 = t & 7;    // 0..7

    {   // load q tile (32 x 64)
        int e0 = g8 * 8;
        const float* src = QKV + ((long)((i * 4 + b) * 256 + nt * 32 + r)) * 2304 + h * 64 + e0;
        *(float4*)&qs[r][e0]     = *(const float4*)src;
        *(float4*)&qs[r][e0 + 4] = *(const float4*)(src + 4);
    }

    float acc[8] = {0.f,0.f,0.f,0.f,0.f,0.f,0.f,0.f};

    for (int j = 0; j < 4; ++j) {
        const float* kbaseP = QKV + ((long)(j * 4 + b) * 256) * 2304 + 768 + h * 64;
        for (int mt = 0; mt < 4; ++mt) {
            __syncthreads();
            {   // stage K tile (64 x 64)
                int mm = t >> 2, e0 = (t & 3) * 16;
                const float* src = kbaseP + (long)(mt * 64 + mm) * 2304 + e0;
                *(float4*)&kv[mm][e0]      = *(const float4*)(src);
                *(float4*)&kv[mm][e0 + 4]  = *(const float4*)(src + 4);
                *(float4*)&kv[mm][e0 + 8]  = *(const float4*)(src + 8);
                *(float4*)&kv[mm][e0 + 12] = *(const float4*)(src + 12);
            }
            __syncthreads();
            #pragma unroll
            for (int mm = 0; mm < 8; ++mm) {
                int m = g8 + mm * 8;
                float d = 0.f;
                #pragma unroll
                for (int e = 0; e < 64; e += 4) {
                    float4 q4 = *(const float4*)&qs[r][e];
                    float4 k4 = *(const float4*)&kv[m][e];
                    d += q4.x * k4.x + q4.y * k4.y + q4.z * k4.z + q4.w * k4.w;
                }
                sc[r][mt * 64 + m] = d * 0.125f;
            }
        }
        __syncthreads();
        {   // softmax over 256 keys, 8 threads per row
            int mb = g8 * 32;
            float lmax = -1e30f;
            for (int m2 = 0; m2 < 32; ++m2) lmax = fmaxf(lmax, sc[r][mb + m2]);
            red[r][g8] = lmax;
            __syncthreads();
            float rmax = red[r][0];
            #pragma unroll
            for (int q = 1; q < 8; ++q) rmax = fmaxf(rmax, red[r][q]);
            float lsum = 0.f;
            for (int m2 = 0; m2 < 32; ++m2) {
                float ev = __expf(sc[r][mb + m2] - rmax);
                sc[r][mb + m2] = ev;
                lsum += ev;
            }
            __syncthreads();
            red[r][g8] = lsum;
            __syncthreads();
            if (g8 == 0) {
                float ssum = 0.f;
                #pragma unroll
                for (int q = 0; q < 8; ++q) ssum += red[r][q];
                invsum[r] = 1.0f / ssum;
            }
        }
        const float* vbaseP = QKV + ((long)(j * 4 + b) * 256) * 2304 + 1536 + h * 64;
        float tmp[8] = {0.f,0.f,0.f,0.f,0.f,0.f,0.f,0.f};
        const int eb = g8 * 8;
        for (int mt = 0; mt < 4; ++mt) {
            __syncthreads();
            {   // stage V tile (64 x 64)
                int mm = t >> 2, e0 = (t & 3) * 16;
                const float* src = vbaseP + (long)(mt * 64 + mm) * 2304 + e0;
                *(float4*)&kv[mm][e0]      = *(const float4*)(src);
                *(float4*)&kv[mm][e0 + 4]  = *(const float4*)(src + 4);
                *(float4*)&kv[mm][e0 + 8]  = *(const float4*)(src + 8);
                *(float4*)&kv[mm][e0 + 12] = *(const float4*)(src + 12);
            }
            __syncthreads();
            for (int mm = 0; mm < 64; ++mm) {
                float p = sc[r][mt * 64 + mm];
                float4 v0 = *(const float4*)&kv[mm][eb];
                float4 v1 = *(const float4*)&kv[mm][eb + 4];
                tmp[0] += p * v0.x; tmp[1] += p * v0.y; tmp[2] += p * v0.z; tmp[3] += p * v0.w;
                tmp[4] += p * v1.x; tmp[5] += p * v1.y; tmp[6] += p * v1.z; tmp[7] += p * v1.w;
            }
        }
        float is = invsum[r];
        #pragma unroll
        for (int c = 0; c < 8; ++c) acc[c] += tmp[c] * is;
    }

    {   // write ctx_mean [V,B,N,C]
        const int eb = g8 * 8;
        float* dst = ctx + ((long)((i * 4 + b) * 256 + nt * 32 + r)) * 768 + h * 64 + eb;
        *(float4*)dst       = make_float4(acc[0]*0.25f, acc[1]*0.25f, acc[2]*0.25f, acc[3]*0.25f);
        *(float4*)(dst + 4) = make_float4(acc[4]*0.25f, acc[5]*0.25f, acc[6]*0.25f, acc[7]*0.25f);
    }
}

// ---------------------------------------------------------------------------
// qh[v,d] = query . wq[v,d,:] + bq[v,d]    (wq = rows [0,768) of mha_in_w)
// ---------------------------------------------------------------------------
__global__ void qh_kernel(const float* __restrict__ query, const float* __restrict__ Win,
                          const float* __restrict__ Bin, float* __restrict__ QH)
{
    int gid = blockIdx.x * 256 + threadIdx.x;  // 0..3071
    int v = gid / 768, d = gid - v * 768;
    const float* w = Win + ((long)v * 2304 + d) * 768;
    float s = 0.f;
    for (int c = 0; c < 768; c += 4) {
        float4 w4 = *(const float4*)(w + c);
        float4 q4 = *(const float4*)(query + c);
        s += q4.x * w4.x + q4.y * w4.y + q4.z * w4.z + q4.w * w4.w;
    }
    QH[gid] = s + Bin[(long)v * 2304 + d];
}

// ---------------------------------------------------------------------------
// Learnable-query cross attention. grid (H,B,V), block 256 (thread = key pos)
// KVH layout [V,B,N,1536]: cols [0,768)=k, [768,1536)=v
// ---------------------------------------------------------------------------
__launch_bounds__(256, 2)
__global__ void cross_attn(const float* __restrict__ KVH, const float* __restrict__ QH,
                           float* __restrict__ C2)
{
    const int h = blockIdx.x, b = blockIdx.y, v = blockIdx.z;
    const int t = threadIdx.x;
    __shared__ float qv[64];
    __shared__ float p[256];
    __shared__ float part[4][64];
    __shared__ float wred[4], wred2[4];

    if (t < 64) qv[t] = QH[(v * 12 + h) * 64 + t];
    __syncthreads();

    const float* krow = KVH + ((long)((v * 4 + b) * 256 + t)) * 1536 + h * 64;
    float s = 0.f;
    #pragma unroll
    for (int e = 0; e < 64; e += 4) {
        float4 k4 = *(const float4*)(krow + e);
        s += qv[e] * k4.x + qv[e + 1] * k4.y + qv[e + 2] * k4.z + qv[e + 3] * k4.w;
    }
    s *= 0.125f;
    float m4 = s;
    #pragma unroll
    for (int off = 32; off > 0; off >>= 1) m4 = fmaxf(m4, __shfl_down(m4, off));
    if ((t & 63) == 0) wred[t >> 6] = m4;
    __syncthreads();
    float rmax = fmaxf(fmaxf(wred[0], wred[1]), fmaxf(wred[2], wred[3]));
    float ev = __expf(s - rmax);
    p[t] = ev;
    float s4 = ev;
    #pragma unroll
    for (int off = 32; off > 0; off >>= 1) s4 += __shfl_down(s4, off);
    if ((t & 63) == 0) wred2[t >> 6] = s4;
    __syncthreads();
    float inv = 1.0f / (wred2[0] + wred2[1] + wred2[2] + wred2[3]);

    const int e = t & 63, ch = t >> 6;
    const float* vbase = KVH + ((long)((v * 4 + b) * 256)) * 1536 + 768 + h * 64 + e;
    float accv = 0.f;
    for (int m = ch * 64; m < ch * 64 + 64; ++m)
        accv += p[m] * vbase[(long)m * 1536];
    part[ch][e] = accv;
    __syncthreads();
    if (t < 64)
        C2[(v * 4 + b) * 768 + h * 64 + t] =
            (part[0][t] + part[1][t] + part[2][t] + part[3][t]) * inv;
}

// ---------------------------------------------------------------------------
// o[v,b,:] = c2[v,b,:] @ Wout[v]^T + bout[v]; broadcast to out[b, n, v*768+d]
// grid 16 (= v*4+b), block 256
// ---------------------------------------------------------------------------
__launch_bounds__(256, 2)
__global__ void out_kernel(const float* __restrict__ C2, const float* __restrict__ Wout,
                           const float* __restrict__ Bout, float* __restrict__ out)
{
    const int bi = blockIdx.x;
    const int v = bi >> 2, b = bi & 3;
    const int t = threadIdx.x;
    __shared__ float c2s[768];
    __shared__ float ov[768];
    for (int c = t; c < 768; c += 256) c2s[c] = C2[(v * 4 + b) * 768 + c];
    __syncthreads();
    for (int d = t; d < 768; d += 256) {
        const float* w = Wout + ((long)v * 768 + d) * 768;
        float s = 0.f;
        for (int c = 0; c < 768; c += 4) {
            float4 w4 = *(const float4*)(w + c);
            s += c2s[c] * w4.x + c2s[c + 1] * w4.y + c2s[c + 2] * w4.z + c2s[c + 3] * w4.w;
        }
        ov[d] = s + Bout[v * 768 + d];
    }
    __syncthreads();
    float* obase = out + (long)b * 256 * 3072 + v * 768;
    for (int n = 0; n < 256; ++n) {
        #pragma unroll
        for (int c3 = 0; c3 < 3; ++c3)
            obase[(long)n * 3072 + c3 * 256 + t] = ov[c3 * 256 + t];
    }
}

// ---------------------------------------------------------------------------
extern "C" void kernel_launch(void* const* d_in, const int* in_sizes, int n_in,
                              void* d_out, int out_size, void* d_ws, size_t ws_size,
                              hipStream_t stream)
{
    const float* X        = (const float*)d_in[0];
    const float* n1g      = (const float*)d_in[1];
    const float* n1b      = (const float*)d_in[2];
    const float* qkv_w    = (const float*)d_in[3];
    const float* proj_w   = (const float*)d_in[4];
    const float* proj_b   = (const float*)d_in[5];
    const float* n2g      = (const float*)d_in[6];
    const float* n2b      = (const float*)d_in[7];
    const float* fc1_w    = (const float*)d_in[8];
    const float* fc1_b    = (const float*)d_in[9];
    const float* fc2_w    = (const float*)d_in[10];
    const float* fc2_b    = (const float*)d_in[11];
    const float* query    = (const float*)d_in[12];
    const float* mha_in_w = (const float*)d_in[13];
    const float* mha_in_b = (const float*)d_in[14];
    const float* mha_out_w= (const float*)d_in[15];
    const float* mha_out_b= (const float*)d_in[16];
    float* out = (float*)d_out;
    float* ws  = (float*)d_ws;

    // workspace regions (floats)
    float* bufA = ws;                 // 3,145,728  (Xn -> ctx_mean -> h -> x2)
    float* bufX = ws + 3145728;       // 3,145,728  (x = 2*proj(...))
    float* bufB = ws + 6291456;       // 12,582,912 (QKV -> h1 -> KVH)
    float* qh   = ws + 18874368;      // 3072
    float* c2   = ws + 18878464;      // 12288

    // 1. LN1 (transposes [B,V,N,C] -> [V,B,N,C])
    ln1_kernel<<<4096, 256, 0, stream>>>(X, n1g, n1b, bufA);
    // 2. QKV = Xn @ qkv_w^T : [V,1024,2304]
    gemm_awt<0><<<dim3(36, 16, 4), 256, 0, stream>>>(bufA, qkv_w, nullptr, nullptr,
                                                     bufB, 1024, 2304, 768,
                                                     2304L * 768, 0, 0, 0);
    // 3. fusion attention -> ctx_mean [V,1024,768] (into bufA)
    fusion_attn<<<dim3(8, 48, 4), 256, 0, stream>>>(bufB, bufA);
    // 4. x = 2*(ctx_mean @ proj_w^T + proj_b) -> bufX
    gemm_awt<4><<<dim3(12, 16, 4), 256, 0, stream>>>(bufA, proj_w, proj_b, nullptr,
                                                     bufX, 1024, 768, 768,
                                                     768L * 768, 0, 768, 0);
    // 5. h = LN2(x) -> bufA
    ln2_kernel<<<4096, 256, 0, stream>>>(bufX, n2g, n2b, bufA);
    // 6. h1 = gelu(h @ fc1_w^T + fc1_b) -> bufB [V,1024,3072]
    gemm_awt<2><<<dim3(48, 16, 4), 256, 0, stream>>>(bufA, fc1_w, fc1_b, nullptr,
                                                     bufB, 1024, 3072, 768,
                                                     3072L * 768, 0, 3072, 0);
    // 7. x2 = x + (h1 @ fc2_w^T + fc2_b) -> bufA
    gemm_awt<3><<<dim3(12, 16, 4), 256, 0, stream>>>(bufB, fc2_w, fc2_b, bufX,
                                                     bufA, 1024, 768, 3072,
                                                     768L * 3072, 0, 768, 0);
    // 8. qh = query @ wq^T + bq
    qh_kernel<<<12, 256, 0, stream>>>(query, mha_in_w, mha_in_b, qh);
    // 9. KVH = x2 @ [wk;wv]^T + [bk;bv] -> bufB [V,1024,1536]
    gemm_awt<1><<<dim3(24, 16, 4), 256, 0, stream>>>(bufA, mha_in_w, mha_in_b, nullptr,
                                                     bufB, 1024, 1536, 768,
                                                     2304L * 768, 768L * 768, 2304, 768);
    // 10. learnable-query attention -> c2 [V,B,768]
    cross_attn<<<dim3(12, 4, 4), 256, 0, stream>>>(bufB, qh, c2);
    // 11. o = c2 @ mha_out_w^T + b, broadcast over N -> out
    out_kernel<<<16, 256, 0, stream>>>(c2, mha_out_w, mha_out_b, out);
}

// Round 2
// 571.461 us; speedup vs baseline: 4.0453x; 4.0453x over previous
//
#include <hip/hip_runtime.h>
#include <math.h>

#define NVIEW 4
#define BATCH 4
#define NSEQ  256
#define CDIM  768
#define HEADS 12
#define HD    64

typedef __attribute__((ext_vector_type(8))) short   short8;
typedef __attribute__((ext_vector_type(8))) unsigned short ushort8;
typedef __attribute__((ext_vector_type(4))) float   float4v;

typedef const __attribute__((address_space(1))) void gas_t;
typedef       __attribute__((address_space(3))) void las_t;

__device__ __forceinline__ unsigned short f2b(float x)
{
    union { float f; unsigned u; } c; c.f = x;
    unsigned r = (c.u + 0x7FFFu + ((c.u >> 16) & 1u)) >> 16;
    return (unsigned short)r;
}

// ---------------------------------------------------------------------------
// f32 -> bf16 conversion (n must be multiple of 8)
// ---------------------------------------------------------------------------
__global__ void conv_bf16(const float* __restrict__ src, unsigned short* __restrict__ dst, int n)
{
    int idx = (blockIdx.x * 256 + threadIdx.x) * 8;
    if (idx >= n) return;
    float4 a = *(const float4*)(src + idx);
    float4 b = *(const float4*)(src + idx + 4);
    ushort8 o;
    o[0] = f2b(a.x); o[1] = f2b(a.y); o[2] = f2b(a.z); o[3] = f2b(a.w);
    o[4] = f2b(b.x); o[5] = f2b(b.y); o[6] = f2b(b.z); o[7] = f2b(b.w);
    *(ushort8*)(dst + idx) = o;
}

// ---------------------------------------------------------------------------
// LayerNorm -> bf16 out
// ---------------------------------------------------------------------------
__device__ __forceinline__ void block_ln_row_b(const float* __restrict__ xrow,
                                               const float* __restrict__ g,
                                               const float* __restrict__ b,
                                               unsigned short* __restrict__ orow)
{
    const int t = threadIdx.x;
    float x0 = xrow[t], x1 = xrow[t + 256], x2 = xrow[t + 512];
    float s  = x0 + x1 + x2;
    float s2 = x0 * x0 + x1 * x1 + x2 * x2;
    #pragma unroll
    for (int off = 32; off > 0; off >>= 1) {
        s  += __shfl_down(s, off);
        s2 += __shfl_down(s2, off);
    }
    __shared__ float w1[4], w2[4];
    if ((t & 63) == 0) { w1[t >> 6] = s; w2[t >> 6] = s2; }
    __syncthreads();
    float S  = w1[0] + w1[1] + w1[2] + w1[3];
    float S2 = w2[0] + w2[1] + w2[2] + w2[3];
    float mean = S * (1.0f / 768.0f);
    float var  = S2 * (1.0f / 768.0f) - mean * mean;
    float inv  = rsqrtf(var + 1e-6f);
    orow[t]       = f2b((x0 - mean) * inv * g[t]       + b[t]);
    orow[t + 256] = f2b((x1 - mean) * inv * g[t + 256] + b[t + 256]);
    orow[t + 512] = f2b((x2 - mean) * inv * g[t + 512] + b[t + 512]);
}

// X:[B,V,N,C] -> Xn bf16 [V,B,N,C]
__global__ void ln1_kernel(const float* __restrict__ X, const float* __restrict__ g,
                           const float* __restrict__ b, unsigned short* __restrict__ Xn)
{
    int rid = blockIdx.x;
    int n  = rid & 255;
    int bv = rid >> 8;
    int bb = bv >> 2, v = bv & 3;
    const float* xrow = X + (long)rid * CDIM;
    unsigned short* orow = Xn + ((long)(v * 4 + bb) * 256 + n) * CDIM;
    block_ln_row_b(xrow, g, b, orow);
}

// f32 in [V,B,N,C] -> bf16 out, per-view gamma/beta
__global__ void ln2_kernel(const float* __restrict__ Xin, const float* __restrict__ g,
                           const float* __restrict__ b, unsigned short* __restrict__ Out)
{
    int rid = blockIdx.x;
    int v = rid >> 10;
    const float* xrow = Xin + (long)rid * CDIM;
    block_ln_row_b(xrow, g + v * CDIM, b + v * CDIM, Out + (long)rid * CDIM);
}

// ---------------------------------------------------------------------------
// bf16 MFMA grouped GEMM: out[v] = A[v](M,K) * W[v]^T(N,K) + epilogue
// 128x128 tile, BK=32, 4 waves in 2x2, 16x16x32 MFMA.
// EPI: 0=none 1=+bias 2=+bias,gelu 3=+bias,+resid(f32) 4=(+bias)*2
// ---------------------------------------------------------------------------
template <typename T> __device__ __forceinline__ void store_val(T* p, float x);
template <> __device__ __forceinline__ void store_val<float>(float* p, float x) { *p = x; }
template <> __device__ __forceinline__ void store_val<unsigned short>(unsigned short* p, float x) { *p = f2b(x); }

template <int EPI, typename OT>
__launch_bounds__(256, 2)
__global__ void gemm_bf16(const unsigned short* __restrict__ A,
                          const unsigned short* __restrict__ W,
                          const float* __restrict__ bias, const float* __restrict__ resid,
                          OT* __restrict__ out, int M, int N, int K,
                          long wStride, long wOff, int bStride, int bOff)
{
    const int v = blockIdx.z;
    const unsigned short* Av = A + (long)v * M * K;
    const unsigned short* Wv = W + v * wStride + wOff;

    __shared__ unsigned short As[128 * 32];
    __shared__ unsigned short Bs[128 * 32];

    const int tid  = threadIdx.x;
    const int lane = tid & 63;
    const int wave = tid >> 6;
    const int l15  = lane & 15;
    const int quad = lane >> 4;
    const int row0 = blockIdx.y * 128, col0 = blockIdx.x * 128;
    const int mw = (wave & 1) * 64, nw = (wave >> 1) * 64;

    float4v acc[4][4];
    #pragma unroll
    for (int i = 0; i < 4; ++i)
        #pragma unroll
        for (int j = 0; j < 4; ++j)
            acc[i][j] = (float4v){0.f, 0.f, 0.f, 0.f};

    const int rA = wave * 32 + (lane >> 2);   // tile row for chunk g=0 (g=1: +16)
    const int pA = lane & 3;                  // physical 16B slot within row

    for (int k0 = 0; k0 < K; k0 += 32) {
        __syncthreads();
        #pragma unroll
        for (int g = 0; g < 2; ++g) {
            int r = rA + g * 16;
            int c = (pA - ((r >> 1) & 3)) & 3;          // logical k-chunk stored at slot pA
            const unsigned short* sa = Av + (long)(row0 + r) * K + k0 + c * 8;
            const unsigned short* sw = Wv + (long)(col0 + r) * K + k0 + c * 8;
            __builtin_amdgcn_global_load_lds((gas_t*)sa, (las_t*)&As[(wave * 32 + g * 16) * 32], 16, 0, 0);
            __builtin_amdgcn_global_load_lds((gas_t*)sw, (las_t*)&Bs[(wave * 32 + g * 16) * 32], 16, 0, 0);
        }
        __syncthreads();

        short8 af[4], bfr[4];
        #pragma unroll
        for (int mi = 0; mi < 4; ++mi) {
            int m = mw + mi * 16 + l15;
            int p = (quad + ((m >> 1) & 3)) & 3;
            af[mi] = *(const short8*)&As[m * 32 + p * 8];
        }
        #pragma unroll
        for (int ni = 0; ni < 4; ++ni) {
            int n = nw + ni * 16 + l15;
            int p = (quad + ((n >> 1) & 3)) & 3;
            bfr[ni] = *(const short8*)&Bs[n * 32 + p * 8];
        }
        #pragma unroll
        for (int mi = 0; mi < 4; ++mi)
            #pragma unroll
            for (int ni = 0; ni < 4; ++ni)
                acc[mi][ni] = __builtin_amdgcn_mfma_f32_16x16x32_bf16(af[mi], bfr[ni], acc[mi][ni], 0, 0, 0);
    }

    #pragma unroll
    for (int mi = 0; mi < 4; ++mi) {
        #pragma unroll
        for (int ni = 0; ni < 4; ++ni) {
            int rowb = row0 + mw + mi * 16 + quad * 4;
            int col  = col0 + nw + ni * 16 + l15;
            float bval = 0.f;
            if (EPI >= 1) bval = bias[v * bStride + bOff + col];
            #pragma unroll
            for (int r = 0; r < 4; ++r) {
                float x = acc[mi][ni][r] + bval;
                if (EPI == 2) x = 0.5f * x * (1.0f + erff(x * 0.70710678118654752f));
                if (EPI == 3) x += resid[(long)v * M * N + (long)(rowb + r) * N + col];
                if (EPI == 4) x *= 2.0f;
                store_val<OT>(out + (long)v * M * N + (long)(rowb + r) * N + col, x);
            }
        }
    }
}

// ---------------------------------------------------------------------------
// Fused MFMA fusion-attention.
// grid (qt=4, b*h=48, i=4); block 256 = 4 waves; each wave owns 16 query rows.
// QKV bf16 [V, B*N, 2304] (q @ h*64, k @ 768+h*64, v @ 1536+h*64).
// ctx_mean bf16 [V, B*N, 768] = 0.25 * sum_j softmax(q_i k_j^T /8) v_j
// ---------------------------------------------------------------------------
__launch_bounds__(256, 2)
__global__ void fusion_attn_mfma(const unsigned short* __restrict__ QKV,
                                 unsigned short* __restrict__ ctx)
{
    const int qt = blockIdx.x;
    const int b  = blockIdx.y / HEADS;
    const int h  = blockIdx.y % HEADS;
    const int i  = blockIdx.z;
    const int tid  = threadIdx.x;
    const int lane = tid & 63;
    const int wave = tid >> 6;
    const int l15  = lane & 15;
    const int quad = lane >> 4;

    __shared__ unsigned short Qs[64 * 72];     //  9216 B, A-operand for S
    __shared__ unsigned short Ks[128 * 64];    // 16384 B, B-operand for S (swizzled)
    __shared__ unsigned short Ps[64 * 136];    // 17408 B, A-operand for PV
    __shared__ unsigned short Vt[64 * 136];    // 17408 B, B-operand for PV (V^T)

    {   // stage Q tile: rows qt*64..+64, cols h*64..+64 -> Qs stride 72
        int r = tid >> 2, p16 = (tid & 3) * 16;
        const unsigned short* src = QKV + ((long)((i * 4 + b) * 256 + qt * 64 + r)) * 2304 + h * 64 + p16;
        *(ushort8*)(&Qs[r * 72 + p16])     = *(const ushort8*)(src);
        *(ushort8*)(&Qs[r * 72 + p16 + 8]) = *(const ushort8*)(src + 8);
    }

    float4v acc_o[4];
    #pragma unroll
    for (int e = 0; e < 4; ++e) acc_o[e] = (float4v){0.f, 0.f, 0.f, 0.f};

    for (int j = 0; j < 4; ++j) {
        const unsigned short* Kb = QKV + ((long)((j * 4 + b) * 256)) * 2304 + 768 + h * 64;
        const unsigned short* Vb = Kb + 768;

        float4v sacc[16];
        #pragma unroll
        for (int t = 0; t < 16; ++t) sacc[t] = (float4v){0.f, 0.f, 0.f, 0.f};

        // ---- S = Q K^T over 2 half-tiles of 128 keys ----
        for (int half = 0; half < 2; ++half) {
            __syncthreads();   // Ks free
            #pragma unroll
            for (int g = 0; g < 4; ++g) {
                int R = wave * 32 + g * 8;
                int r = R + (lane >> 3);
                int p = lane & 7;
                int c = (p - (r & 7)) & 7;
                const unsigned short* src = Kb + (long)(half * 128 + r) * 2304 + c * 8;
                __builtin_amdgcn_global_load_lds((gas_t*)src, (las_t*)&Ks[R * 64], 16, 0, 0);
            }
            __syncthreads();
            #pragma unroll
            for (int ks = 0; ks < 2; ++ks) {
                int lcq = ks * 4 + quad;
                short8 qf = *(const short8*)&Qs[(wave * 16 + l15) * 72 + lcq * 8];
                #pragma unroll
                for (int nn = 0; nn < 8; ++nn) {
                    int n = nn * 16 + l15;
                    int p = (lcq + (n & 7)) & 7;
                    short8 kf = *(const short8*)&Ks[n * 64 + p * 8];
                    sacc[half * 8 + nn] =
                        __builtin_amdgcn_mfma_f32_16x16x32_bf16(qf, kf, sacc[half * 8 + nn], 0, 0, 0);
                }
            }
        }

        // ---- softmax over 256 cols, rows = quad*4 + r, reduce over 16 lanes ----
        float rmax[4] = {-1e30f, -1e30f, -1e30f, -1e30f};
        #pragma unroll
        for (int t = 0; t < 16; ++t)
            #pragma unroll
            for (int r = 0; r < 4; ++r)
                rmax[r] = fmaxf(rmax[r], sacc[t][r] * 0.125f);
        #pragma unroll
        for (int off = 1; off < 16; off <<= 1)
            #pragma unroll
            for (int r = 0; r < 4; ++r)
                rmax[r] = fmaxf(rmax[r], __shfl_xor(rmax[r], off));
        float rsum[4] = {0.f, 0.f, 0.f, 0.f};
        #pragma unroll
        for (int t = 0; t < 16; ++t)
            #pragma unroll
            for (int r = 0; r < 4; ++r) {
                float e = __expf(sacc[t][r] * 0.125f - rmax[r]);
                sacc[t][r] = e;
                rsum[r] += e;
            }
        #pragma unroll
        for (int off = 1; off < 16; off <<= 1)
            #pragma unroll
            for (int r = 0; r < 4; ++r)
                rsum[r] += __shfl_xor(rsum[r], off);
        float invl[4];
        #pragma unroll
        for (int r = 0; r < 4; ++r) invl[r] = 1.0f / rsum[r];

        // ---- PV over 2 half-tiles ----
        float4v pv[4];
        #pragma unroll
        for (int e = 0; e < 4; ++e) pv[e] = (float4v){0.f, 0.f, 0.f, 0.f};

        for (int half = 0; half < 2; ++half) {
            __syncthreads();   // Ps/Vt free
            // write this wave's P rows (bf16, unnormalized)
            #pragma unroll
            for (int nn = 0; nn < 8; ++nn)
                #pragma unroll
                for (int r = 0; r < 4; ++r)
                    Ps[(wave * 16 + quad * 4 + r) * 136 + nn * 16 + l15] = f2b(sacc[half * 8 + nn][r]);
            // stage V^T: thread handles key n = tid&127, d-chunks (tid>>7)*4..+4
            {
                int n = tid & 127;
                int c0 = (tid >> 7) * 4;
                #pragma unroll
                for (int cc = 0; cc < 4; ++cc) {
                    int c = c0 + cc;
                    ushort8 vv = *(const ushort8*)(Vb + (long)(half * 128 + n) * 2304 + c * 8);
                    #pragma unroll
                    for (int jj = 0; jj < 8; ++jj)
                        Vt[(c * 8 + jj) * 136 + n] = vv[jj];
                }
            }
            __syncthreads();
            #pragma unroll
            for (int ks = 0; ks < 4; ++ks) {
                int lc = ks * 4 + quad;
                short8 pf = *(const short8*)&Ps[(wave * 16 + l15) * 136 + lc * 8];
                #pragma unroll
                for (int et = 0; et < 4; ++et) {
                    short8 vf = *(const short8*)&Vt[(et * 16 + l15) * 136 + lc * 8];
                    pv[et] = __builtin_amdgcn_mfma_f32_16x16x32_bf16(pf, vf, pv[et], 0, 0, 0);
                }
            }
        }
        #pragma unroll
        for (int et = 0; et < 4; ++et)
            #pragma unroll
            for (int r = 0; r < 4; ++r)
                acc_o[et][r] += pv[et][r] * invl[r];
    }

    // ---- write ctx_mean (scale 0.25) ----
    #pragma unroll
    for (int et = 0; et < 4; ++et)
        #pragma unroll
        for (int r = 0; r < 4; ++r) {
            int row = (i * 4 + b) * 256 + qt * 64 + wave * 16 + quad * 4 + r;
            int col = h * 64 + et * 16 + l15;
            ctx[(long)row * 768 + col] = f2b(acc_o[et][r] * 0.25f);
        }
}

// ---------------------------------------------------------------------------
// qh[v,d] = query . wq[v,d,:] + bq[v,d]   (f32 weights direct)
// ---------------------------------------------------------------------------
__global__ void qh_kernel(const float* __restrict__ query, const float* __restrict__ Win,
                          const float* __restrict__ Bin, float* __restrict__ QH)
{
    int gid = blockIdx.x * 256 + threadIdx.x;
    int v = gid / 768, d = gid - v * 768;
    const float* w = Win + ((long)v * 2304 + d) * 768;
    float s = 0.f;
    for (int c = 0; c < 768; c += 4) {
        float4 w4 = *(const float4*)(w + c);
        float4 q4 = *(const float4*)(query + c);
        s += q4.x * w4.x + q4.y * w4.y + q4.z * w4.z + q4.w * w4.w;
    }
    QH[gid] = s + Bin[(long)v * 2304 + d];
}

// ---------------------------------------------------------------------------
// Learnable-query cross attention (f32). KVH [V,B,N,1536]: k then v.
// ---------------------------------------------------------------------------
__launch_bounds__(256, 2)
__global__ void cross_attn(const float* __restrict__ KVH, const float* __restrict__ QH,
                           float* __restrict__ C2)
{
    const int h = blockIdx.x, b = blockIdx.y, v = blockIdx.z;
    const int t = threadIdx.x;
    __shared__ float qv[64];
    __shared__ float p[256];
    __shared__ float part[4][64];
    __shared__ float wred[4], wred2[4];

    if (t < 64) qv[t] = QH[(v * 12 + h) * 64 + t];
    __syncthreads();

    const float* krow = KVH + ((long)((v * 4 + b) * 256 + t)) * 1536 + h * 64;
    float s = 0.f;
    #pragma unroll
    for (int e = 0; e < 64; e += 4) {
        float4 k4 = *(const float4*)(krow + e);
        s += qv[e] * k4.x + qv[e + 1] * k4.y + qv[e + 2] * k4.z + qv[e + 3] * k4.w;
    }
    s *= 0.125f;
    float m4 = s;
    #pragma unroll
    for (int off = 32; off > 0; off >>= 1) m4 = fmaxf(m4, __shfl_down(m4, off));
    if ((t & 63) == 0) wred[t >> 6] = m4;
    __syncthreads();
    float rmax = fmaxf(fmaxf(wred[0], wred[1]), fmaxf(wred[2], wred[3]));
    float ev = __expf(s - rmax);
    p[t] = ev;
    float s4 = ev;
    #pragma unroll
    for (int off = 32; off > 0; off >>= 1) s4 += __shfl_down(s4, off);
    if ((t & 63) == 0) wred2[t >> 6] = s4;
    __syncthreads();
    float inv = 1.0f / (wred2[0] + wred2[1] + wred2[2] + wred2[3]);

    const int e = t & 63, ch = t >> 6;
    const float* vbase = KVH + ((long)((v * 4 + b) * 256)) * 1536 + 768 + h * 64 + e;
    float accv = 0.f;
    for (int m = ch * 64; m < ch * 64 + 64; ++m)
        accv += p[m] * vbase[(long)m * 1536];
    part[ch][e] = accv;
    __syncthreads();
    if (t < 64)
        C2[(v * 4 + b) * 768 + h * 64 + t] =
            (part[0][t] + part[1][t] + part[2][t] + part[3][t]) * inv;
}

// ---------------------------------------------------------------------------
// o = c2 @ Wout^T + b; broadcast over N into out[b,n,v*768+d]
// ---------------------------------------------------------------------------
__launch_bounds__(256, 2)
__global__ void out_kernel(const float* __restrict__ C2, const float* __restrict__ Wout,
                           const float* __restrict__ Bout, float* __restrict__ out)
{
    const int bi = blockIdx.x;
    const int v = bi >> 2, b = bi & 3;
    const int t = threadIdx.x;
    __shared__ float c2s[768];
    __shared__ float ov[768];
    for (int c = t; c < 768; c += 256) c2s[c] = C2[(v * 4 + b) * 768 + c];
    __syncthreads();
    for (int d = t; d < 768; d += 256) {
        const float* w = Wout + ((long)v * 768 + d) * 768;
        float s = 0.f;
        for (int c = 0; c < 768; c += 4) {
            float4 w4 = *(const float4*)(w + c);
            s += c2s[c] * w4.x + c2s[c + 1] * w4.y + c2s[c + 2] * w4.z + c2s[c + 3] * w4.w;
        }
        ov[d] = s + Bout[v * 768 + d];
    }
    __syncthreads();
    float* obase = out + (long)b * 256 * 3072 + v * 768;
    for (int n = 0; n < 256; ++n) {
        #pragma unroll
        for (int c3 = 0; c3 < 3; ++c3)
            obase[(long)n * 3072 + c3 * 256 + t] = ov[c3 * 256 + t];
    }
}

// ---------------------------------------------------------------------------
extern "C" void kernel_launch(void* const* d_in, const int* in_sizes, int n_in,
                              void* d_out, int out_size, void* d_ws, size_t ws_size,
                              hipStream_t stream)
{
    const float* X        = (const float*)d_in[0];
    const float* n1g      = (const float*)d_in[1];
    const float* n1b      = (const float*)d_in[2];
    const float* qkv_w    = (const float*)d_in[3];
    const float* proj_w   = (const float*)d_in[4];
    const float* proj_b   = (const float*)d_in[5];
    const float* n2g      = (const float*)d_in[6];
    const float* n2b      = (const float*)d_in[7];
    const float* fc1_w    = (const float*)d_in[8];
    const float* fc1_b    = (const float*)d_in[9];
    const float* fc2_w    = (const float*)d_in[10];
    const float* fc2_b    = (const float*)d_in[11];
    const float* query    = (const float*)d_in[12];
    const float* mha_in_w = (const float*)d_in[13];
    const float* mha_in_b = (const float*)d_in[14];
    const float* mha_out_w= (const float*)d_in[15];
    const float* mha_out_b= (const float*)d_in[16];
    float* out = (float*)d_out;

    char* wsb = (char*)d_ws;
    unsigned short* wbuf = (unsigned short*)wsb;                    // 18,874,368 B (weight scratch, reused)
    unsigned short* rgA  = (unsigned short*)(wsb + 18874368);       //  6,291,456 B (Xn -> ctx -> h -> x2)
    char*           rgB  = wsb + 25165824;                          // 25,165,824 B (QKV -> h1 -> KVH)
    float*          xbuf = (float*)(wsb + 50331648);                // 12,582,912 B (x residual, f32)
    float*          qh   = (float*)(wsb + 62914560);
    float*          c2   = (float*)(wsb + 62926848);

    unsigned short* QKV = (unsigned short*)rgB;
    unsigned short* H1  = (unsigned short*)rgB;
    float*          KVH = (float*)rgB;

    // 1. weights -> bf16 (qkv), LN1 -> Xn bf16
    conv_bf16<<<3456, 256, 0, stream>>>(qkv_w, wbuf, 7077888);
    ln1_kernel<<<4096, 256, 0, stream>>>(X, n1g, n1b, rgA);
    // 2. QKV = Xn @ qkv_w^T  [V,1024,2304] bf16
    gemm_bf16<0, unsigned short><<<dim3(18, 8, 4), 256, 0, stream>>>(
        rgA, wbuf, nullptr, nullptr, QKV, 1024, 2304, 768, 2304L * 768, 0, 0, 0);
    // 3. fusion attention -> ctx_mean bf16 [V,1024,768]
    fusion_attn_mfma<<<dim3(4, 48, 4), 256, 0, stream>>>(QKV, rgA);
    // 4. x = 2*(ctx @ proj_w^T + proj_b)  f32
    conv_bf16<<<1152, 256, 0, stream>>>(proj_w, wbuf, 2359296);
    gemm_bf16<4, float><<<dim3(6, 8, 4), 256, 0, stream>>>(
        rgA, wbuf, proj_b, nullptr, xbuf, 1024, 768, 768, 768L * 768, 0, 768, 0);
    // 5. h = LN2(x) bf16
    ln2_kernel<<<4096, 256, 0, stream>>>(xbuf, n2g, n2b, rgA);
    // 6. h1 = gelu(h @ fc1_w^T + fc1_b) bf16 [V,1024,3072]
    conv_bf16<<<4608, 256, 0, stream>>>(fc1_w, wbuf, 9437184);
    gemm_bf16<2, unsigned short><<<dim3(24, 8, 4), 256, 0, stream>>>(
        rgA, wbuf, fc1_b, nullptr, H1, 1024, 3072, 768, 3072L * 768, 0, 3072, 0);
    // 7. x2 = x + (h1 @ fc2_w^T + fc2_b) bf16
    conv_bf16<<<4608, 256, 0, stream>>>(fc2_w, wbuf, 9437184);
    gemm_bf16<3, unsigned short><<<dim3(6, 8, 4), 256, 0, stream>>>(
        H1, wbuf, fc2_b, xbuf, rgA, 1024, 768, 3072, 768L * 3072, 0, 768, 0);
    // 8. KVH = x2 @ [wk;wv]^T + [bk;bv]  f32 [V,1024,1536]
    conv_bf16<<<3456, 256, 0, stream>>>(mha_in_w, wbuf, 7077888);
    gemm_bf16<1, float><<<dim3(12, 8, 4), 256, 0, stream>>>(
        rgA, wbuf, mha_in_b, nullptr, KVH, 1024, 1536, 768, 2304L * 768, 768L * 768, 2304, 768);
    // 9. small f32 tail
    qh_kernel<<<12, 256, 0, stream>>>(query, mha_in_w, mha_in_b, qh);
    cross_attn<<<dim3(12, 4, 4), 256, 0, stream>>>(KVH, qh, c2);
    out_kernel<<<16, 256, 0, stream>>>(c2, mha_out_w, mha_out_b, out);
}

// Round 3
// 565.223 us; speedup vs baseline: 4.0900x; 1.0110x over previous
//
#include <hip/hip_runtime.h>
#include <math.h>

#define NVIEW 4
#define BATCH 4
#define NSEQ  256
#define CDIM  768
#define HEADS 12
#define HD    64

typedef __attribute__((ext_vector_type(8))) short   short8;
typedef __attribute__((ext_vector_type(8))) unsigned short ushort8;
typedef __attribute__((ext_vector_type(4))) float   float4v;

typedef const __attribute__((address_space(1))) void gas_t;
typedef       __attribute__((address_space(3))) void las_t;

__device__ __forceinline__ unsigned short f2b(float x)
{
    union { float f; unsigned u; } c; c.f = x;
    unsigned r = (c.u + 0x7FFFu + ((c.u >> 16) & 1u)) >> 16;
    return (unsigned short)r;
}

// ---------------------------------------------------------------------------
// f32 -> bf16 conversion (n must be multiple of 8)
// ---------------------------------------------------------------------------
__global__ void conv_bf16(const float* __restrict__ src, unsigned short* __restrict__ dst, int n)
{
    int idx = (blockIdx.x * 256 + threadIdx.x) * 8;
    if (idx >= n) return;
    float4 a = *(const float4*)(src + idx);
    float4 b = *(const float4*)(src + idx + 4);
    ushort8 o;
    o[0] = f2b(a.x); o[1] = f2b(a.y); o[2] = f2b(a.z); o[3] = f2b(a.w);
    o[4] = f2b(b.x); o[5] = f2b(b.y); o[6] = f2b(b.z); o[7] = f2b(b.w);
    *(ushort8*)(dst + idx) = o;
}

// ---------------------------------------------------------------------------
// LayerNorm -> bf16 out
// ---------------------------------------------------------------------------
__device__ __forceinline__ void block_ln_row_b(const float* __restrict__ xrow,
                                               const float* __restrict__ g,
                                               const float* __restrict__ b,
                                               unsigned short* __restrict__ orow)
{
    const int t = threadIdx.x;
    float x0 = xrow[t], x1 = xrow[t + 256], x2 = xrow[t + 512];
    float s  = x0 + x1 + x2;
    float s2 = x0 * x0 + x1 * x1 + x2 * x2;
    #pragma unroll
    for (int off = 32; off > 0; off >>= 1) {
        s  += __shfl_down(s, off);
        s2 += __shfl_down(s2, off);
    }
    __shared__ float w1[4], w2[4];
    if ((t & 63) == 0) { w1[t >> 6] = s; w2[t >> 6] = s2; }
    __syncthreads();
    float S  = w1[0] + w1[1] + w1[2] + w1[3];
    float S2 = w2[0] + w2[1] + w2[2] + w2[3];
    float mean = S * (1.0f / 768.0f);
    float var  = S2 * (1.0f / 768.0f) - mean * mean;
    float inv  = rsqrtf(var + 1e-6f);
    orow[t]       = f2b((x0 - mean) * inv * g[t]       + b[t]);
    orow[t + 256] = f2b((x1 - mean) * inv * g[t + 256] + b[t + 256]);
    orow[t + 512] = f2b((x2 - mean) * inv * g[t + 512] + b[t + 512]);
}

// X:[B,V,N,C] -> Xn bf16 [V,B,N,C]
__global__ void ln1_kernel(const float* __restrict__ X, const float* __restrict__ g,
                           const float* __restrict__ b, unsigned short* __restrict__ Xn)
{
    int rid = blockIdx.x;
    int n  = rid & 255;
    int bv = rid >> 8;
    int bb = bv >> 2, v = bv & 3;
    const float* xrow = X + (long)rid * CDIM;
    unsigned short* orow = Xn + ((long)(v * 4 + bb) * 256 + n) * CDIM;
    block_ln_row_b(xrow, g, b, orow);
}

// f32 in [V,B,N,C] -> bf16 out, per-view gamma/beta
__global__ void ln2_kernel(const float* __restrict__ Xin, const float* __restrict__ g,
                           const float* __restrict__ b, unsigned short* __restrict__ Out)
{
    int rid = blockIdx.x;
    int v = rid >> 10;
    const float* xrow = Xin + (long)rid * CDIM;
    block_ln_row_b(xrow, g + v * CDIM, b + v * CDIM, Out + (long)rid * CDIM);
}

// ---------------------------------------------------------------------------
// bf16 MFMA grouped GEMM: out[v] = A[v](M,K) * W[v]^T(N,K) + epilogue
// 128x128 tile, BK=32, 4 waves in 2x2, 16x16x32 MFMA.
// EPI: 0=none 1=+bias 2=+bias,gelu 3=+bias,+resid(f32) 4=(+bias)*2
// ---------------------------------------------------------------------------
template <typename T> __device__ __forceinline__ void store_val(T* p, float x);
template <> __device__ __forceinline__ void store_val<float>(float* p, float x) { *p = x; }
template <> __device__ __forceinline__ void store_val<unsigned short>(unsigned short* p, float x) { *p = f2b(x); }

template <int EPI, typename OT>
__launch_bounds__(256, 2)
__global__ void gemm_bf16(const unsigned short* __restrict__ A,
                          const unsigned short* __restrict__ W,
                          const float* __restrict__ bias, const float* __restrict__ resid,
                          OT* __restrict__ out, int M, int N, int K,
                          long wStride, long wOff, int bStride, int bOff)
{
    const int v = blockIdx.z;
    const unsigned short* Av = A + (long)v * M * K;
    const unsigned short* Wv = W + v * wStride + wOff;

    __shared__ unsigned short As[128 * 32];
    __shared__ unsigned short Bs[128 * 32];

    const int tid  = threadIdx.x;
    const int lane = tid & 63;
    const int wave = tid >> 6;
    const int l15  = lane & 15;
    const int quad = lane >> 4;
    const int row0 = blockIdx.y * 128, col0 = blockIdx.x * 128;
    const int mw = (wave & 1) * 64, nw = (wave >> 1) * 64;

    float4v acc[4][4];
    #pragma unroll
    for (int i = 0; i < 4; ++i)
        #pragma unroll
        for (int j = 0; j < 4; ++j)
            acc[i][j] = (float4v){0.f, 0.f, 0.f, 0.f};

    const int rA = wave * 32 + (lane >> 2);   // tile row for chunk g=0 (g=1: +16)
    const int pA = lane & 3;                  // physical 16B slot within row

    for (int k0 = 0; k0 < K; k0 += 32) {
        __syncthreads();
        #pragma unroll
        for (int g = 0; g < 2; ++g) {
            int r = rA + g * 16;
            int c = (pA - ((r >> 1) & 3)) & 3;          // logical k-chunk stored at slot pA
            const unsigned short* sa = Av + (long)(row0 + r) * K + k0 + c * 8;
            const unsigned short* sw = Wv + (long)(col0 + r) * K + k0 + c * 8;
            __builtin_amdgcn_global_load_lds((gas_t*)sa, (las_t*)&As[(wave * 32 + g * 16) * 32], 16, 0, 0);
            __builtin_amdgcn_global_load_lds((gas_t*)sw, (las_t*)&Bs[(wave * 32 + g * 16) * 32], 16, 0, 0);
        }
        __syncthreads();

        short8 af[4], bfr[4];
        #pragma unroll
        for (int mi = 0; mi < 4; ++mi) {
            int m = mw + mi * 16 + l15;
            int p = (quad + ((m >> 1) & 3)) & 3;
            af[mi] = *(const short8*)&As[m * 32 + p * 8];
        }
        #pragma unroll
        for (int ni = 0; ni < 4; ++ni) {
            int n = nw + ni * 16 + l15;
            int p = (quad + ((n >> 1) & 3)) & 3;
            bfr[ni] = *(const short8*)&Bs[n * 32 + p * 8];
        }
        #pragma unroll
        for (int mi = 0; mi < 4; ++mi)
            #pragma unroll
            for (int ni = 0; ni < 4; ++ni)
                acc[mi][ni] = __builtin_amdgcn_mfma_f32_16x16x32_bf16(af[mi], bfr[ni], acc[mi][ni], 0, 0, 0);
    }

    #pragma unroll
    for (int mi = 0; mi < 4; ++mi) {
        #pragma unroll
        for (int ni = 0; ni < 4; ++ni) {
            int rowb = row0 + mw + mi * 16 + quad * 4;
            int col  = col0 + nw + ni * 16 + l15;
            float bval = 0.f;
            if (EPI >= 1) bval = bias[v * bStride + bOff + col];
            #pragma unroll
            for (int r = 0; r < 4; ++r) {
                float x = acc[mi][ni][r] + bval;
                if (EPI == 2) x = 0.5f * x * (1.0f + erff(x * 0.70710678118654752f));
                if (EPI == 3) x += resid[(long)v * M * N + (long)(rowb + r) * N + col];
                if (EPI == 4) x *= 2.0f;
                store_val<OT>(out + (long)v * M * N + (long)(rowb + r) * N + col, x);
            }
        }
    }
}

// ---------------------------------------------------------------------------
// Fused MFMA fusion-attention.
// grid (qt=4, b*h=48, i=4); block 256 = 4 waves; each wave owns 16 query rows.
// ---------------------------------------------------------------------------
__launch_bounds__(256, 2)
__global__ void fusion_attn_mfma(const unsigned short* __restrict__ QKV,
                                 unsigned short* __restrict__ ctx)
{
    const int qt = blockIdx.x;
    const int b  = blockIdx.y / HEADS;
    const int h  = blockIdx.y % HEADS;
    const int i  = blockIdx.z;
    const int tid  = threadIdx.x;
    const int lane = tid & 63;
    const int wave = tid >> 6;
    const int l15  = lane & 15;
    const int quad = lane >> 4;

    __shared__ unsigned short Qs[64 * 72];
    __shared__ unsigned short Ks[128 * 64];
    __shared__ unsigned short Ps[64 * 136];
    __shared__ unsigned short Vt[64 * 136];

    {   // stage Q tile
        int r = tid >> 2, p16 = (tid & 3) * 16;
        const unsigned short* src = QKV + ((long)((i * 4 + b) * 256 + qt * 64 + r)) * 2304 + h * 64 + p16;
        *(ushort8*)(&Qs[r * 72 + p16])     = *(const ushort8*)(src);
        *(ushort8*)(&Qs[r * 72 + p16 + 8]) = *(const ushort8*)(src + 8);
    }

    float4v acc_o[4];
    #pragma unroll
    for (int e = 0; e < 4; ++e) acc_o[e] = (float4v){0.f, 0.f, 0.f, 0.f};

    for (int j = 0; j < 4; ++j) {
        const unsigned short* Kb = QKV + ((long)((j * 4 + b) * 256)) * 2304 + 768 + h * 64;
        const unsigned short* Vb = Kb + 768;

        float4v sacc[16];
        #pragma unroll
        for (int t = 0; t < 16; ++t) sacc[t] = (float4v){0.f, 0.f, 0.f, 0.f};

        for (int half = 0; half < 2; ++half) {
            __syncthreads();
            #pragma unroll
            for (int g = 0; g < 4; ++g) {
                int R = wave * 32 + g * 8;
                int r = R + (lane >> 3);
                int p = lane & 7;
                int c = (p - (r & 7)) & 7;
                const unsigned short* src = Kb + (long)(half * 128 + r) * 2304 + c * 8;
                __builtin_amdgcn_global_load_lds((gas_t*)src, (las_t*)&Ks[R * 64], 16, 0, 0);
            }
            __syncthreads();
            #pragma unroll
            for (int ks = 0; ks < 2; ++ks) {
                int lcq = ks * 4 + quad;
                short8 qf = *(const short8*)&Qs[(wave * 16 + l15) * 72 + lcq * 8];
                #pragma unroll
                for (int nn = 0; nn < 8; ++nn) {
                    int n = nn * 16 + l15;
                    int p = (lcq + (n & 7)) & 7;
                    short8 kf = *(const short8*)&Ks[n * 64 + p * 8];
                    sacc[half * 8 + nn] =
                        __builtin_amdgcn_mfma_f32_16x16x32_bf16(qf, kf, sacc[half * 8 + nn], 0, 0, 0);
                }
            }
        }

        float rmax[4] = {-1e30f, -1e30f, -1e30f, -1e30f};
        #pragma unroll
        for (int t = 0; t < 16; ++t)
            #pragma unroll
            for (int r = 0; r < 4; ++r)
                rmax[r] = fmaxf(rmax[r], sacc[t][r] * 0.125f);
        #pragma unroll
        for (int off = 1; off < 16; off <<= 1)
            #pragma unroll
            for (int r = 0; r < 4; ++r)
                rmax[r] = fmaxf(rmax[r], __shfl_xor(rmax[r], off));
        float rsum[4] = {0.f, 0.f, 0.f, 0.f};
        #pragma unroll
        for (int t = 0; t < 16; ++t)
            #pragma unroll
            for (int r = 0; r < 4; ++r) {
                float e = __expf(sacc[t][r] * 0.125f - rmax[r]);
                sacc[t][r] = e;
                rsum[r] += e;
            }
        #pragma unroll
        for (int off = 1; off < 16; off <<= 1)
            #pragma unroll
            for (int r = 0; r < 4; ++r)
                rsum[r] += __shfl_xor(rsum[r], off);
        float invl[4];
        #pragma unroll
        for (int r = 0; r < 4; ++r) invl[r] = 1.0f / rsum[r];

        float4v pv[4];
        #pragma unroll
        for (int e = 0; e < 4; ++e) pv[e] = (float4v){0.f, 0.f, 0.f, 0.f};

        for (int half = 0; half < 2; ++half) {
            __syncthreads();
            #pragma unroll
            for (int nn = 0; nn < 8; ++nn)
                #pragma unroll
                for (int r = 0; r < 4; ++r)
                    Ps[(wave * 16 + quad * 4 + r) * 136 + nn * 16 + l15] = f2b(sacc[half * 8 + nn][r]);
            {
                int n = tid & 127;
                int c0 = (tid >> 7) * 4;
                #pragma unroll
                for (int cc = 0; cc < 4; ++cc) {
                    int c = c0 + cc;
                    ushort8 vv = *(const ushort8*)(Vb + (long)(half * 128 + n) * 2304 + c * 8);
                    #pragma unroll
                    for (int jj = 0; jj < 8; ++jj)
                        Vt[(c * 8 + jj) * 136 + n] = vv[jj];
                }
            }
            __syncthreads();
            #pragma unroll
            for (int ks = 0; ks < 4; ++ks) {
                int lc = ks * 4 + quad;
                short8 pf = *(const short8*)&Ps[(wave * 16 + l15) * 136 + lc * 8];
                #pragma unroll
                for (int et = 0; et < 4; ++et) {
                    short8 vf = *(const short8*)&Vt[(et * 16 + l15) * 136 + lc * 8];
                    pv[et] = __builtin_amdgcn_mfma_f32_16x16x32_bf16(pf, vf, pv[et], 0, 0, 0);
                }
            }
        }
        #pragma unroll
        for (int et = 0; et < 4; ++et)
            #pragma unroll
            for (int r = 0; r < 4; ++r)
                acc_o[et][r] += pv[et][r] * invl[r];
    }

    #pragma unroll
    for (int et = 0; et < 4; ++et)
        #pragma unroll
        for (int r = 0; r < 4; ++r) {
            int row = (i * 4 + b) * 256 + qt * 64 + wave * 16 + quad * 4 + r;
            int col = h * 64 + et * 16 + l15;
            ctx[(long)row * 768 + col] = f2b(acc_o[et][r] * 0.25f);
        }
}

// ---------------------------------------------------------------------------
// qh[v,d] = query . wq[v,d,:] + bq[v,d]
// ---------------------------------------------------------------------------
__global__ void qh_kernel(const float* __restrict__ query, const float* __restrict__ Win,
                          const float* __restrict__ Bin, float* __restrict__ QH)
{
    int gid = blockIdx.x * 256 + threadIdx.x;
    int v = gid / 768, d = gid - v * 768;
    const float* w = Win + ((long)v * 2304 + d) * 768;
    float s = 0.f;
    for (int c = 0; c < 768; c += 4) {
        float4 w4 = *(const float4*)(w + c);
        float4 q4 = *(const float4*)(query + c);
        s += q4.x * w4.x + q4.y * w4.y + q4.z * w4.z + q4.w * w4.w;
    }
    QH[gid] = s + Bin[(long)v * 2304 + d];
}

// ---------------------------------------------------------------------------
// Learnable-query cross attention (f32). KVH [V,B,N,1536]: k then v.
// ---------------------------------------------------------------------------
__launch_bounds__(256, 2)
__global__ void cross_attn(const float* __restrict__ KVH, const float* __restrict__ QH,
                           float* __restrict__ C2)
{
    const int h = blockIdx.x, b = blockIdx.y, v = blockIdx.z;
    const int t = threadIdx.x;
    __shared__ float qv[64];
    __shared__ float p[256];
    __shared__ float part[4][64];
    __shared__ float wred[4], wred2[4];

    if (t < 64) qv[t] = QH[(v * 12 + h) * 64 + t];
    __syncthreads();

    const float* krow = KVH + ((long)((v * 4 + b) * 256 + t)) * 1536 + h * 64;
    float s = 0.f;
    #pragma unroll
    for (int e = 0; e < 64; e += 4) {
        float4 k4 = *(const float4*)(krow + e);
        s += qv[e] * k4.x + qv[e + 1] * k4.y + qv[e + 2] * k4.z + qv[e + 3] * k4.w;
    }
    s *= 0.125f;
    float m4 = s;
    #pragma unroll
    for (int off = 32; off > 0; off >>= 1) m4 = fmaxf(m4, __shfl_down(m4, off));
    if ((t & 63) == 0) wred[t >> 6] = m4;
    __syncthreads();
    float rmax = fmaxf(fmaxf(wred[0], wred[1]), fmaxf(wred[2], wred[3]));
    float ev = __expf(s - rmax);
    p[t] = ev;
    float s4 = ev;
    #pragma unroll
    for (int off = 32; off > 0; off >>= 1) s4 += __shfl_down(s4, off);
    if ((t & 63) == 0) wred2[t >> 6] = s4;
    __syncthreads();
    float inv = 1.0f / (wred2[0] + wred2[1] + wred2[2] + wred2[3]);

    const int e = t & 63, ch = t >> 6;
    const float* vbase = KVH + ((long)((v * 4 + b) * 256)) * 1536 + 768 + h * 64 + e;
    float accv = 0.f;
    for (int m = ch * 64; m < ch * 64 + 64; ++m)
        accv += p[m] * vbase[(long)m * 1536];
    part[ch][e] = accv;
    __syncthreads();
    if (t < 64)
        C2[(v * 4 + b) * 768 + h * 64 + t] =
            (part[0][t] + part[1][t] + part[2][t] + part[3][t]) * inv;
}

// ---------------------------------------------------------------------------
// out stage 1: obc[b][v*768+d] = c2[v,b,:] . Wout[v,d,:] + Bout[v,d]
// grid 16 (= v*4+b), block 256
// ---------------------------------------------------------------------------
__launch_bounds__(256, 2)
__global__ void out_matvec(const float* __restrict__ C2, const float* __restrict__ Wout,
                           const float* __restrict__ Bout, float* __restrict__ obc)
{
    const int bi = blockIdx.x;
    const int v = bi >> 2, b = bi & 3;
    const int t = threadIdx.x;
    __shared__ float c2s[768];
    for (int c = t; c < 768; c += 256) c2s[c] = C2[(v * 4 + b) * 768 + c];
    __syncthreads();
    for (int d = t; d < 768; d += 256) {
        const float* w = Wout + ((long)v * 768 + d) * 768;
        float s = 0.f;
        for (int c = 0; c < 768; c += 4) {
            float4 w4 = *(const float4*)(w + c);
            s += c2s[c] * w4.x + c2s[c + 1] * w4.y + c2s[c + 2] * w4.z + c2s[c + 3] * w4.w;
        }
        obc[(long)b * 3072 + v * 768 + d] = s + Bout[v * 768 + d];
    }
}

// ---------------------------------------------------------------------------
// out stage 2: out[(b*256+n)*3072 + k] = obc[b][k] for all n
// grid 256 (b = blk>>6, 4 rows each), block 256; float4 copies
// ---------------------------------------------------------------------------
__launch_bounds__(256, 4)
__global__ void out_bcast(const float* __restrict__ obc, float* __restrict__ out)
{
    const int b  = blockIdx.x >> 6;
    const int n0 = (blockIdx.x & 63) * 4;
    const int t  = threadIdx.x;
    const float4* src = (const float4*)(obc + (long)b * 3072);
    float4 v0 = src[t], v1 = src[t + 256], v2 = src[t + 512];
    float4* dst = (float4*)(out + ((long)(b * 256 + n0)) * 3072);
    #pragma unroll
    for (int r = 0; r < 4; ++r) {
        dst[r * 768 + t]       = v0;
        dst[r * 768 + t + 256] = v1;
        dst[r * 768 + t + 512] = v2;
    }
}

// ---------------------------------------------------------------------------
extern "C" void kernel_launch(void* const* d_in, const int* in_sizes, int n_in,
                              void* d_out, int out_size, void* d_ws, size_t ws_size,
                              hipStream_t stream)
{
    const float* X        = (const float*)d_in[0];
    const float* n1g      = (const float*)d_in[1];
    const float* n1b      = (const float*)d_in[2];
    const float* qkv_w    = (const float*)d_in[3];
    const float* proj_w   = (const float*)d_in[4];
    const float* proj_b   = (const float*)d_in[5];
    const float* n2g      = (const float*)d_in[6];
    const float* n2b      = (const float*)d_in[7];
    const float* fc1_w    = (const float*)d_in[8];
    const float* fc1_b    = (const float*)d_in[9];
    const float* fc2_w    = (const float*)d_in[10];
    const float* fc2_b    = (const float*)d_in[11];
    const float* query    = (const float*)d_in[12];
    const float* mha_in_w = (const float*)d_in[13];
    const float* mha_in_b = (const float*)d_in[14];
    const float* mha_out_w= (const float*)d_in[15];
    const float* mha_out_b= (const float*)d_in[16];
    float* out = (float*)d_out;

    char* wsb = (char*)d_ws;
    unsigned short* wbuf = (unsigned short*)wsb;                    // 18,874,368 B (weight scratch, reused)
    unsigned short* rgA  = (unsigned short*)(wsb + 18874368);       //  6,291,456 B (Xn -> ctx -> h -> x2)
    char*           rgB  = wsb + 25165824;                          // 25,165,824 B (QKV -> h1 -> KVH)
    float*          xbuf = (float*)(wsb + 50331648);                // 12,582,912 B (x residual, f32)
    float*          qh   = (float*)(wsb + 62914560);
    float*          c2   = (float*)(wsb + 62926848);
    float*          obc  = (float*)(wsb + 62976000);                // 49,152 B

    unsigned short* QKV = (unsigned short*)rgB;
    unsigned short* H1  = (unsigned short*)rgB;
    float*          KVH = (float*)rgB;

    // 1. weights -> bf16 (qkv), LN1 -> Xn bf16
    conv_bf16<<<3456, 256, 0, stream>>>(qkv_w, wbuf, 7077888);
    ln1_kernel<<<4096, 256, 0, stream>>>(X, n1g, n1b, rgA);
    // 2. QKV = Xn @ qkv_w^T  [V,1024,2304] bf16
    gemm_bf16<0, unsigned short><<<dim3(18, 8, 4), 256, 0, stream>>>(
        rgA, wbuf, nullptr, nullptr, QKV, 1024, 2304, 768, 2304L * 768, 0, 0, 0);
    // 3. fusion attention -> ctx_mean bf16 [V,1024,768]
    fusion_attn_mfma<<<dim3(4, 48, 4), 256, 0, stream>>>(QKV, rgA);
    // 4. x = 2*(ctx @ proj_w^T + proj_b)  f32
    conv_bf16<<<1152, 256, 0, stream>>>(proj_w, wbuf, 2359296);
    gemm_bf16<4, float><<<dim3(6, 8, 4), 256, 0, stream>>>(
        rgA, wbuf, proj_b, nullptr, xbuf, 1024, 768, 768, 768L * 768, 0, 768, 0);
    // 5. h = LN2(x) bf16
    ln2_kernel<<<4096, 256, 0, stream>>>(xbuf, n2g, n2b, rgA);
    // 6. h1 = gelu(h @ fc1_w^T + fc1_b) bf16 [V,1024,3072]
    conv_bf16<<<4608, 256, 0, stream>>>(fc1_w, wbuf, 9437184);
    gemm_bf16<2, unsigned short><<<dim3(24, 8, 4), 256, 0, stream>>>(
        rgA, wbuf, fc1_b, nullptr, H1, 1024, 3072, 768, 3072L * 768, 0, 3072, 0);
    // 7. x2 = x + (h1 @ fc2_w^T + fc2_b) bf16
    conv_bf16<<<4608, 256, 0, stream>>>(fc2_w, wbuf, 9437184);
    gemm_bf16<3, unsigned short><<<dim3(6, 8, 4), 256, 0, stream>>>(
        H1, wbuf, fc2_b, xbuf, rgA, 1024, 768, 3072, 768L * 3072, 0, 768, 0);
    // 8. KVH = x2 @ [wk;wv]^T + [bk;bv]  f32 [V,1024,1536]
    conv_bf16<<<3456, 256, 0, stream>>>(mha_in_w, wbuf, 7077888);
    gemm_bf16<1, float><<<dim3(12, 8, 4), 256, 0, stream>>>(
        rgA, wbuf, mha_in_b, nullptr, KVH, 1024, 1536, 768, 2304L * 768, 768L * 768, 2304, 768);
    // 9. small tail
    qh_kernel<<<12, 256, 0, stream>>>(query, mha_in_w, mha_in_b, qh);
    cross_attn<<<dim3(12, 4, 4), 256, 0, stream>>>(KVH, qh, c2);
    out_matvec<<<16, 256, 0, stream>>>(c2, mha_out_w, mha_out_b, obc);
    out_bcast<<<256, 256, 0, stream>>>(obc, out);
}

// Round 4
// 495.967 us; speedup vs baseline: 4.6611x; 1.1396x over previous
//
#include <hip/hip_runtime.h>
#include <math.h>

#define NVIEW 4
#define BATCH 4
#define NSEQ  256
#define CDIM  768
#define HEADS 12
#define HD    64

typedef __attribute__((ext_vector_type(8))) short   short8;
typedef __attribute__((ext_vector_type(8))) unsigned short ushort8;
typedef __attribute__((ext_vector_type(4))) float   float4v;

typedef const __attribute__((address_space(1))) void gas_t;
typedef       __attribute__((address_space(3))) void las_t;

__device__ __forceinline__ unsigned short f2b(float x)
{
    union { float f; unsigned u; } c; c.f = x;
    unsigned r = (c.u + 0x7FFFu + ((c.u >> 16) & 1u)) >> 16;
    return (unsigned short)r;
}

// ---------------------------------------------------------------------------
// f32 -> bf16 conversion (n must be multiple of 8)
// ---------------------------------------------------------------------------
__global__ void conv_bf16(const float* __restrict__ src, unsigned short* __restrict__ dst, int n)
{
    int idx = (blockIdx.x * 256 + threadIdx.x) * 8;
    if (idx >= n) return;
    float4 a = *(const float4*)(src + idx);
    float4 b = *(const float4*)(src + idx + 4);
    ushort8 o;
    o[0] = f2b(a.x); o[1] = f2b(a.y); o[2] = f2b(a.z); o[3] = f2b(a.w);
    o[4] = f2b(b.x); o[5] = f2b(b.y); o[6] = f2b(b.z); o[7] = f2b(b.w);
    *(ushort8*)(dst + idx) = o;
}

// ---------------------------------------------------------------------------
// LayerNorm -> bf16 out
// ---------------------------------------------------------------------------
__device__ __forceinline__ void block_ln_row_b(const float* __restrict__ xrow,
                                               const float* __restrict__ g,
                                               const float* __restrict__ b,
                                               unsigned short* __restrict__ orow)
{
    const int t = threadIdx.x;
    float x0 = xrow[t], x1 = xrow[t + 256], x2 = xrow[t + 512];
    float s  = x0 + x1 + x2;
    float s2 = x0 * x0 + x1 * x1 + x2 * x2;
    #pragma unroll
    for (int off = 32; off > 0; off >>= 1) {
        s  += __shfl_down(s, off);
        s2 += __shfl_down(s2, off);
    }
    __shared__ float w1[4], w2[4];
    if ((t & 63) == 0) { w1[t >> 6] = s; w2[t >> 6] = s2; }
    __syncthreads();
    float S  = w1[0] + w1[1] + w1[2] + w1[3];
    float S2 = w2[0] + w2[1] + w2[2] + w2[3];
    float mean = S * (1.0f / 768.0f);
    float var  = S2 * (1.0f / 768.0f) - mean * mean;
    float inv  = rsqrtf(var + 1e-6f);
    orow[t]       = f2b((x0 - mean) * inv * g[t]       + b[t]);
    orow[t + 256] = f2b((x1 - mean) * inv * g[t + 256] + b[t + 256]);
    orow[t + 512] = f2b((x2 - mean) * inv * g[t + 512] + b[t + 512]);
}

// X:[B,V,N,C] -> Xn bf16 [V,B,N,C]
__global__ void ln1_kernel(const float* __restrict__ X, const float* __restrict__ g,
                           const float* __restrict__ b, unsigned short* __restrict__ Xn)
{
    int rid = blockIdx.x;
    int n  = rid & 255;
    int bv = rid >> 8;
    int bb = bv >> 2, v = bv & 3;
    const float* xrow = X + (long)rid * CDIM;
    unsigned short* orow = Xn + ((long)(v * 4 + bb) * 256 + n) * CDIM;
    block_ln_row_b(xrow, g, b, orow);
}

// f32 in [V,B,N,C] -> bf16 out, per-view gamma/beta
__global__ void ln2_kernel(const float* __restrict__ Xin, const float* __restrict__ g,
                           const float* __restrict__ b, unsigned short* __restrict__ Out)
{
    int rid = blockIdx.x;
    int v = rid >> 10;
    const float* xrow = Xin + (long)rid * CDIM;
    block_ln_row_b(xrow, g + v * CDIM, b + v * CDIM, Out + (long)rid * CDIM);
}

// ---------------------------------------------------------------------------
// bf16 MFMA grouped GEMM: out[v] = A[v](M,K) * W[v]^T(N,K) + epilogue
// 128x128 tile, BK=32, 4 waves in 2x2, 16x16x32 MFMA.
// EPI: 0=none 1=+bias 2=+bias,gelu 3=+bias,+resid(f32) 4=(+bias)*2
// ---------------------------------------------------------------------------
template <typename T> __device__ __forceinline__ void store_val(T* p, float x);
template <> __device__ __forceinline__ void store_val<float>(float* p, float x) { *p = x; }
template <> __device__ __forceinline__ void store_val<unsigned short>(unsigned short* p, float x) { *p = f2b(x); }

template <int EPI, typename OT>
__launch_bounds__(256, 2)
__global__ void gemm_bf16(const unsigned short* __restrict__ A,
                          const unsigned short* __restrict__ W,
                          const float* __restrict__ bias, const float* __restrict__ resid,
                          OT* __restrict__ out, int M, int N, int K,
                          long wStride, long wOff, int bStride, int bOff)
{
    const int v = blockIdx.z;
    const unsigned short* Av = A + (long)v * M * K;
    const unsigned short* Wv = W + v * wStride + wOff;

    __shared__ unsigned short As[128 * 32];
    __shared__ unsigned short Bs[128 * 32];

    const int tid  = threadIdx.x;
    const int lane = tid & 63;
    const int wave = tid >> 6;
    const int l15  = lane & 15;
    const int quad = lane >> 4;
    const int row0 = blockIdx.y * 128, col0 = blockIdx.x * 128;
    const int mw = (wave & 1) * 64, nw = (wave >> 1) * 64;

    float4v acc[4][4];
    #pragma unroll
    for (int i = 0; i < 4; ++i)
        #pragma unroll
        for (int j = 0; j < 4; ++j)
            acc[i][j] = (float4v){0.f, 0.f, 0.f, 0.f};

    const int rA = wave * 32 + (lane >> 2);   // tile row for chunk g=0 (g=1: +16)
    const int pA = lane & 3;                  // physical 16B slot within row

    for (int k0 = 0; k0 < K; k0 += 32) {
        __syncthreads();
        #pragma unroll
        for (int g = 0; g < 2; ++g) {
            int r = rA + g * 16;
            int c = (pA - ((r >> 1) & 3)) & 3;          // logical k-chunk stored at slot pA
            const unsigned short* sa = Av + (long)(row0 + r) * K + k0 + c * 8;
            const unsigned short* sw = Wv + (long)(col0 + r) * K + k0 + c * 8;
            __builtin_amdgcn_global_load_lds((gas_t*)sa, (las_t*)&As[(wave * 32 + g * 16) * 32], 16, 0, 0);
            __builtin_amdgcn_global_load_lds((gas_t*)sw, (las_t*)&Bs[(wave * 32 + g * 16) * 32], 16, 0, 0);
        }
        __syncthreads();

        short8 af[4], bfr[4];
        #pragma unroll
        for (int mi = 0; mi < 4; ++mi) {
            int m = mw + mi * 16 + l15;
            int p = (quad + ((m >> 1) & 3)) & 3;
            af[mi] = *(const short8*)&As[m * 32 + p * 8];
        }
        #pragma unroll
        for (int ni = 0; ni < 4; ++ni) {
            int n = nw + ni * 16 + l15;
            int p = (quad + ((n >> 1) & 3)) & 3;
            bfr[ni] = *(const short8*)&Bs[n * 32 + p * 8];
        }
        #pragma unroll
        for (int mi = 0; mi < 4; ++mi)
            #pragma unroll
            for (int ni = 0; ni < 4; ++ni)
                acc[mi][ni] = __builtin_amdgcn_mfma_f32_16x16x32_bf16(af[mi], bfr[ni], acc[mi][ni], 0, 0, 0);
    }

    #pragma unroll
    for (int mi = 0; mi < 4; ++mi) {
        #pragma unroll
        for (int ni = 0; ni < 4; ++ni) {
            int rowb = row0 + mw + mi * 16 + quad * 4;
            int col  = col0 + nw + ni * 16 + l15;
            float bval = 0.f;
            if (EPI >= 1) bval = bias[v * bStride + bOff + col];
            #pragma unroll
            for (int r = 0; r < 4; ++r) {
                float x = acc[mi][ni][r] + bval;
                if (EPI == 2) x = 0.5f * x * (1.0f + erff(x * 0.70710678118654752f));
                if (EPI == 3) x += resid[(long)v * M * N + (long)(rowb + r) * N + col];
                if (EPI == 4) x *= 2.0f;
                store_val<OT>(out + (long)v * M * N + (long)(rowb + r) * N + col, x);
            }
        }
    }
}

// ---------------------------------------------------------------------------
// Fused MFMA fusion-attention.
// grid (qt=4, b*h=48, i=4); block 256 = 4 waves; each wave owns 16 query rows.
// ---------------------------------------------------------------------------
__launch_bounds__(256, 2)
__global__ void fusion_attn_mfma(const unsigned short* __restrict__ QKV,
                                 unsigned short* __restrict__ ctx)
{
    const int qt = blockIdx.x;
    const int b  = blockIdx.y / HEADS;
    const int h  = blockIdx.y % HEADS;
    const int i  = blockIdx.z;
    const int tid  = threadIdx.x;
    const int lane = tid & 63;
    const int wave = tid >> 6;
    const int l15  = lane & 15;
    const int quad = lane >> 4;

    __shared__ unsigned short Qs[64 * 72];
    __shared__ unsigned short Ks[128 * 64];
    __shared__ unsigned short Ps[64 * 136];
    __shared__ unsigned short Vt[64 * 136];

    {   // stage Q tile
        int r = tid >> 2, p16 = (tid & 3) * 16;
        const unsigned short* src = QKV + ((long)((i * 4 + b) * 256 + qt * 64 + r)) * 2304 + h * 64 + p16;
        *(ushort8*)(&Qs[r * 72 + p16])     = *(const ushort8*)(src);
        *(ushort8*)(&Qs[r * 72 + p16 + 8]) = *(const ushort8*)(src + 8);
    }

    float4v acc_o[4];
    #pragma unroll
    for (int e = 0; e < 4; ++e) acc_o[e] = (float4v){0.f, 0.f, 0.f, 0.f};

    for (int j = 0; j < 4; ++j) {
        const unsigned short* Kb = QKV + ((long)((j * 4 + b) * 256)) * 2304 + 768 + h * 64;
        const unsigned short* Vb = Kb + 768;

        float4v sacc[16];
        #pragma unroll
        for (int t = 0; t < 16; ++t) sacc[t] = (float4v){0.f, 0.f, 0.f, 0.f};

        for (int half = 0; half < 2; ++half) {
            __syncthreads();
            #pragma unroll
            for (int g = 0; g < 4; ++g) {
                int R = wave * 32 + g * 8;
                int r = R + (lane >> 3);
                int p = lane & 7;
                int c = (p - (r & 7)) & 7;
                const unsigned short* src = Kb + (long)(half * 128 + r) * 2304 + c * 8;
                __builtin_amdgcn_global_load_lds((gas_t*)src, (las_t*)&Ks[R * 64], 16, 0, 0);
            }
            __syncthreads();
            #pragma unroll
            for (int ks = 0; ks < 2; ++ks) {
                int lcq = ks * 4 + quad;
                short8 qf = *(const short8*)&Qs[(wave * 16 + l15) * 72 + lcq * 8];
                #pragma unroll
                for (int nn = 0; nn < 8; ++nn) {
                    int n = nn * 16 + l15;
                    int p = (lcq + (n & 7)) & 7;
                    short8 kf = *(const short8*)&Ks[n * 64 + p * 8];
                    sacc[half * 8 + nn] =
                        __builtin_amdgcn_mfma_f32_16x16x32_bf16(qf, kf, sacc[half * 8 + nn], 0, 0, 0);
                }
            }
        }

        float rmax[4] = {-1e30f, -1e30f, -1e30f, -1e30f};
        #pragma unroll
        for (int t = 0; t < 16; ++t)
            #pragma unroll
            for (int r = 0; r < 4; ++r)
                rmax[r] = fmaxf(rmax[r], sacc[t][r] * 0.125f);
        #pragma unroll
        for (int off = 1; off < 16; off <<= 1)
            #pragma unroll
            for (int r = 0; r < 4; ++r)
                rmax[r] = fmaxf(rmax[r], __shfl_xor(rmax[r], off));
        float rsum[4] = {0.f, 0.f, 0.f, 0.f};
        #pragma unroll
        for (int t = 0; t < 16; ++t)
            #pragma unroll
            for (int r = 0; r < 4; ++r) {
                float e = __expf(sacc[t][r] * 0.125f - rmax[r]);
                sacc[t][r] = e;
                rsum[r] += e;
            }
        #pragma unroll
        for (int off = 1; off < 16; off <<= 1)
            #pragma unroll
            for (int r = 0; r < 4; ++r)
                rsum[r] += __shfl_xor(rsum[r], off);
        float invl[4];
        #pragma unroll
        for (int r = 0; r < 4; ++r) invl[r] = 1.0f / rsum[r];

        float4v pv[4];
        #pragma unroll
        for (int e = 0; e < 4; ++e) pv[e] = (float4v){0.f, 0.f, 0.f, 0.f};

        for (int half = 0; half < 2; ++half) {
            __syncthreads();
            #pragma unroll
            for (int nn = 0; nn < 8; ++nn)
                #pragma unroll
                for (int r = 0; r < 4; ++r)
                    Ps[(wave * 16 + quad * 4 + r) * 136 + nn * 16 + l15] = f2b(sacc[half * 8 + nn][r]);
            {
                int n = tid & 127;
                int c0 = (tid >> 7) * 4;
                #pragma unroll
                for (int cc = 0; cc < 4; ++cc) {
                    int c = c0 + cc;
                    ushort8 vv = *(const ushort8*)(Vb + (long)(half * 128 + n) * 2304 + c * 8);
                    #pragma unroll
                    for (int jj = 0; jj < 8; ++jj)
                        Vt[(c * 8 + jj) * 136 + n] = vv[jj];
                }
            }
            __syncthreads();
            #pragma unroll
            for (int ks = 0; ks < 4; ++ks) {
                int lc = ks * 4 + quad;
                short8 pf = *(const short8*)&Ps[(wave * 16 + l15) * 136 + lc * 8];
                #pragma unroll
                for (int et = 0; et < 4; ++et) {
                    short8 vf = *(const short8*)&Vt[(et * 16 + l15) * 136 + lc * 8];
                    pv[et] = __builtin_amdgcn_mfma_f32_16x16x32_bf16(pf, vf, pv[et], 0, 0, 0);
                }
            }
        }
        #pragma unroll
        for (int et = 0; et < 4; ++et)
            #pragma unroll
            for (int r = 0; r < 4; ++r)
                acc_o[et][r] += pv[et][r] * invl[r];
    }

    #pragma unroll
    for (int et = 0; et < 4; ++et)
        #pragma unroll
        for (int r = 0; r < 4; ++r) {
            int row = (i * 4 + b) * 256 + qt * 64 + wave * 16 + quad * 4 + r;
            int col = h * 64 + et * 16 + l15;
            ctx[(long)row * 768 + col] = f2b(acc_o[et][r] * 0.25f);
        }
}

// ---------------------------------------------------------------------------
// qh[v,d] = query . wq[v,d,:] + bq[v,d]
// ---------------------------------------------------------------------------
__global__ void qh_kernel(const float* __restrict__ query, const float* __restrict__ Win,
                          const float* __restrict__ Bin, float* __restrict__ QH)
{
    int gid = blockIdx.x * 256 + threadIdx.x;
    int v = gid / 768, d = gid - v * 768;
    const float* w = Win + ((long)v * 2304 + d) * 768;
    float s = 0.f;
    for (int c = 0; c < 768; c += 4) {
        float4 w4 = *(const float4*)(w + c);
        float4 q4 = *(const float4*)(query + c);
        s += q4.x * w4.x + q4.y * w4.y + q4.z * w4.z + q4.w * w4.w;
    }
    QH[gid] = s + Bin[(long)v * 2304 + d];
}

// ---------------------------------------------------------------------------
// Learnable-query cross attention (f32). KVH [V,B,N,1536]: k then v.
// ---------------------------------------------------------------------------
__launch_bounds__(256, 2)
__global__ void cross_attn(const float* __restrict__ KVH, const float* __restrict__ QH,
                           float* __restrict__ C2)
{
    const int h = blockIdx.x, b = blockIdx.y, v = blockIdx.z;
    const int t = threadIdx.x;
    __shared__ float qv[64];
    __shared__ float p[256];
    __shared__ float part[4][64];
    __shared__ float wred[4], wred2[4];

    if (t < 64) qv[t] = QH[(v * 12 + h) * 64 + t];
    __syncthreads();

    const float* krow = KVH + ((long)((v * 4 + b) * 256 + t)) * 1536 + h * 64;
    float s = 0.f;
    #pragma unroll
    for (int e = 0; e < 64; e += 4) {
        float4 k4 = *(const float4*)(krow + e);
        s += qv[e] * k4.x + qv[e + 1] * k4.y + qv[e + 2] * k4.z + qv[e + 3] * k4.w;
    }
    s *= 0.125f;
    float m4 = s;
    #pragma unroll
    for (int off = 32; off > 0; off >>= 1) m4 = fmaxf(m4, __shfl_down(m4, off));
    if ((t & 63) == 0) wred[t >> 6] = m4;
    __syncthreads();
    float rmax = fmaxf(fmaxf(wred[0], wred[1]), fmaxf(wred[2], wred[3]));
    float ev = __expf(s - rmax);
    p[t] = ev;
    float s4 = ev;
    #pragma unroll
    for (int off = 32; off > 0; off >>= 1) s4 += __shfl_down(s4, off);
    if ((t & 63) == 0) wred2[t >> 6] = s4;
    __syncthreads();
    float inv = 1.0f / (wred2[0] + wred2[1] + wred2[2] + wred2[3]);

    const int e = t & 63, ch = t >> 6;
    const float* vbase = KVH + ((long)((v * 4 + b) * 256)) * 1536 + 768 + h * 64 + e;
    float accv = 0.f;
    for (int m = ch * 64; m < ch * 64 + 64; ++m)
        accv += p[m] * vbase[(long)m * 1536];
    part[ch][e] = accv;
    __syncthreads();
    if (t < 64)
        C2[(v * 4 + b) * 768 + h * 64 + t] =
            (part[0][t] + part[1][t] + part[2][t] + part[3][t]) * inv;
}

// ---------------------------------------------------------------------------
// out stage 1 (parallel): one wave per output row d; 768 blocks x 4 waves.
// obc[b][v*768+d] = c2[v,b,:] . Wout[v,d,:] + Bout[v,d]
// weights read exactly once device-wide; c2 slab (v) staged in LDS.
// ---------------------------------------------------------------------------
__launch_bounds__(256, 4)
__global__ void out_matvec(const float* __restrict__ C2, const float* __restrict__ Wout,
                           const float* __restrict__ Bout, float* __restrict__ obc)
{
    const int bi   = blockIdx.x;            // 0..767
    const int v    = bi / 192;
    const int dblk = bi - v * 192;
    const int t    = threadIdx.x;
    const int wave = t >> 6;
    const int lane = t & 63;
    const int d    = dblk * 4 + wave;

    __shared__ float c2s[3072];             // c2[v, b=0..3, 0..767]
    #pragma unroll
    for (int idx = 0; idx < 3072; idx += 256) c2s[idx + t] = C2[v * 3072 + idx + t];
    __syncthreads();

    const float* w = Wout + ((long)v * 768 + d) * 768;
    float acc0 = 0.f, acc1 = 0.f, acc2 = 0.f, acc3 = 0.f;
    #pragma unroll
    for (int k = 0; k < 3; ++k) {
        int c = k * 256 + lane * 4;
        float4 w4 = *(const float4*)(w + c);
        float4 a0 = *(const float4*)&c2s[c];
        float4 a1 = *(const float4*)&c2s[768 + c];
        float4 a2 = *(const float4*)&c2s[1536 + c];
        float4 a3 = *(const float4*)&c2s[2304 + c];
        acc0 += w4.x * a0.x + w4.y * a0.y + w4.z * a0.z + w4.w * a0.w;
        acc1 += w4.x * a1.x + w4.y * a1.y + w4.z * a1.z + w4.w * a1.w;
        acc2 += w4.x * a2.x + w4.y * a2.y + w4.z * a2.z + w4.w * a2.w;
        acc3 += w4.x * a3.x + w4.y * a3.y + w4.z * a3.z + w4.w * a3.w;
    }
    #pragma unroll
    for (int off = 32; off > 0; off >>= 1) {
        acc0 += __shfl_down(acc0, off);
        acc1 += __shfl_down(acc1, off);
        acc2 += __shfl_down(acc2, off);
        acc3 += __shfl_down(acc3, off);
    }
    if (lane == 0) {
        float bb = Bout[v * 768 + d];
        obc[0 * 3072 + v * 768 + d] = acc0 + bb;
        obc[1 * 3072 + v * 768 + d] = acc1 + bb;
        obc[2 * 3072 + v * 768 + d] = acc2 + bb;
        obc[3 * 3072 + v * 768 + d] = acc3 + bb;
    }
}

// ---------------------------------------------------------------------------
// out stage 2: out[(b*256+n)*3072 + k] = obc[b][k] for all n
// ---------------------------------------------------------------------------
__launch_bounds__(256, 4)
__global__ void out_bcast(const float* __restrict__ obc, float* __restrict__ out)
{
    const int b  = blockIdx.x >> 6;
    const int n0 = (blockIdx.x & 63) * 4;
    const int t  = threadIdx.x;
    const float4* src = (const float4*)(obc + (long)b * 3072);
    float4 v0 = src[t], v1 = src[t + 256], v2 = src[t + 512];
    float4* dst = (float4*)(out + ((long)(b * 256 + n0)) * 3072);
    #pragma unroll
    for (int r = 0; r < 4; ++r) {
        dst[r * 768 + t]       = v0;
        dst[r * 768 + t + 256] = v1;
        dst[r * 768 + t + 512] = v2;
    }
}

// ---------------------------------------------------------------------------
extern "C" void kernel_launch(void* const* d_in, const int* in_sizes, int n_in,
                              void* d_out, int out_size, void* d_ws, size_t ws_size,
                              hipStream_t stream)
{
    const float* X        = (const float*)d_in[0];
    const float* n1g      = (const float*)d_in[1];
    const float* n1b      = (const float*)d_in[2];
    const float* qkv_w    = (const float*)d_in[3];
    const float* proj_w   = (const float*)d_in[4];
    const float* proj_b   = (const float*)d_in[5];
    const float* n2g      = (const float*)d_in[6];
    const float* n2b      = (const float*)d_in[7];
    const float* fc1_w    = (const float*)d_in[8];
    const float* fc1_b    = (const float*)d_in[9];
    const float* fc2_w    = (const float*)d_in[10];
    const float* fc2_b    = (const float*)d_in[11];
    const float* query    = (const float*)d_in[12];
    const float* mha_in_w = (const float*)d_in[13];
    const float* mha_in_b = (const float*)d_in[14];
    const float* mha_out_w= (const float*)d_in[15];
    const float* mha_out_b= (const float*)d_in[16];
    float* out = (float*)d_out;

    char* wsb = (char*)d_ws;
    unsigned short* wbuf = (unsigned short*)wsb;                    // 18,874,368 B (weight scratch, reused)
    unsigned short* rgA  = (unsigned short*)(wsb + 18874368);       //  6,291,456 B (Xn -> ctx -> h -> x2)
    char*           rgB  = wsb + 25165824;                          // 25,165,824 B (QKV -> h1 -> KVH)
    float*          xbuf = (float*)(wsb + 50331648);                // 12,582,912 B (x residual, f32)
    float*          qh   = (float*)(wsb + 62914560);
    float*          c2   = (float*)(wsb + 62926848);
    float*          obc  = (float*)(wsb + 62976000);                // 49,152 B

    unsigned short* QKV = (unsigned short*)rgB;
    unsigned short* H1  = (unsigned short*)rgB;
    float*          KVH = (float*)rgB;

    // 1. weights -> bf16 (qkv), LN1 -> Xn bf16
    conv_bf16<<<3456, 256, 0, stream>>>(qkv_w, wbuf, 7077888);
    ln1_kernel<<<4096, 256, 0, stream>>>(X, n1g, n1b, rgA);
    // 2. QKV = Xn @ qkv_w^T  [V,1024,2304] bf16
    gemm_bf16<0, unsigned short><<<dim3(18, 8, 4), 256, 0, stream>>>(
        rgA, wbuf, nullptr, nullptr, QKV, 1024, 2304, 768, 2304L * 768, 0, 0, 0);
    // 3. fusion attention -> ctx_mean bf16 [V,1024,768]
    fusion_attn_mfma<<<dim3(4, 48, 4), 256, 0, stream>>>(QKV, rgA);
    // 4. x = 2*(ctx @ proj_w^T + proj_b)  f32
    conv_bf16<<<1152, 256, 0, stream>>>(proj_w, wbuf, 2359296);
    gemm_bf16<4, float><<<dim3(6, 8, 4), 256, 0, stream>>>(
        rgA, wbuf, proj_b, nullptr, xbuf, 1024, 768, 768, 768L * 768, 0, 768, 0);
    // 5. h = LN2(x) bf16
    ln2_kernel<<<4096, 256, 0, stream>>>(xbuf, n2g, n2b, rgA);
    // 6. h1 = gelu(h @ fc1_w^T + fc1_b) bf16 [V,1024,3072]
    conv_bf16<<<4608, 256, 0, stream>>>(fc1_w, wbuf, 9437184);
    gemm_bf16<2, unsigned short><<<dim3(24, 8, 4), 256, 0, stream>>>(
        rgA, wbuf, fc1_b, nullptr, H1, 1024, 3072, 768, 3072L * 768, 0, 3072, 0);
    // 7. x2 = x + (h1 @ fc2_w^T + fc2_b) bf16
    conv_bf16<<<4608, 256, 0, stream>>>(fc2_w, wbuf, 9437184);
    gemm_bf16<3, unsigned short><<<dim3(6, 8, 4), 256, 0, stream>>>(
        H1, wbuf, fc2_b, xbuf, rgA, 1024, 768, 3072, 768L * 3072, 0, 768, 0);
    // 8. KVH = x2 @ [wk;wv]^T + [bk;bv]  f32 [V,1024,1536]
    conv_bf16<<<3456, 256, 0, stream>>>(mha_in_w, wbuf, 7077888);
    gemm_bf16<1, float><<<dim3(12, 8, 4), 256, 0, stream>>>(
        rgA, wbuf, mha_in_b, nullptr, KVH, 1024, 1536, 768, 2304L * 768, 768L * 768, 2304, 768);
    // 9. small tail
    qh_kernel<<<12, 256, 0, stream>>>(query, mha_in_w, mha_in_b, qh);
    cross_attn<<<dim3(12, 4, 4), 256, 0, stream>>>(KVH, qh, c2);
    out_matvec<<<768, 256, 0, stream>>>(c2, mha_out_w, mha_out_b, obc);
    out_bcast<<<256, 256, 0, stream>>>(obc, out);
}